// Round 1
// baseline (1122.380 us; speedup 1.0000x reference)
//
#include <hip/hip_runtime.h>

#define ENC 1024
#define HD 4096
#define OUTROWS 49152   // DIM*BOT = 768*64

__device__ __forceinline__ float wave_sum(float v) {
#pragma unroll
    for (int o = 32; o > 0; o >>= 1) v += __shfl_xor(v, o, 64);
    return v;
}
__device__ __forceinline__ float wave_max(float v) {
#pragma unroll
    for (int o = 32; o > 0; o >>= 1) v = fmaxf(v, __shfl_xor(v, o, 64));
    return v;
}

// h = relu(W1 @ x + b1) : 4096 rows x 1024. One wave per row.
__global__ __launch_bounds__(256) void k_h(const float* __restrict__ W1,
                                           const float* __restrict__ x,
                                           const float* __restrict__ b1,
                                           float* __restrict__ h) {
    const int lane = threadIdx.x & 63;
    const int row  = (blockIdx.x * 256 + threadIdx.x) >> 6;
    const float4* Wr = (const float4*)(W1 + (size_t)row * ENC);
    const float4* x4 = (const float4*)x;
    float acc = 0.f;
#pragma unroll
    for (int k = 0; k < ENC / 256; ++k) {   // 4 float4 per lane
        float4 w  = Wr[lane + 64 * k];
        float4 xv = x4[lane + 64 * k];
        acc = fmaf(w.x, xv.x, acc);
        acc = fmaf(w.y, xv.y, acc);
        acc = fmaf(w.z, xv.z, acc);
        acc = fmaf(w.w, xv.w, acc);
    }
    acc = wave_sum(acc);
    if (lane == 0) h[row] = fmaxf(acc + b1[row], 0.f);
}

// Q/K/V = W{q,k,v} @ h + b : 3*4096 rows x 4096. One wave per row; h staged in LDS.
__global__ __launch_bounds__(256) void k_qkv(const float* __restrict__ Wq,
                                             const float* __restrict__ Wk,
                                             const float* __restrict__ Wv,
                                             const float* __restrict__ bq,
                                             const float* __restrict__ bk,
                                             const float* __restrict__ bv,
                                             const float* __restrict__ h,
                                             float* __restrict__ Q,
                                             float* __restrict__ K,
                                             float* __restrict__ V) {
    __shared__ float4 xs[HD / 4];
    const float4* h4 = (const float4*)h;
#pragma unroll
    for (int k = 0; k < HD / 4 / 256; ++k)   // 4 float4 per thread
        xs[threadIdx.x + 256 * k] = h4[threadIdx.x + 256 * k];
    __syncthreads();

    const int lane = threadIdx.x & 63;
    const int gw   = (blockIdx.x * 256 + threadIdx.x) >> 6;
    const int mat  = gw >> 12;           // 0=Q 1=K 2=V (wave-uniform)
    const int row  = gw & (HD - 1);
    const float* W = (mat == 0) ? Wq : (mat == 1) ? Wk : Wv;
    const float* b = (mat == 0) ? bq : (mat == 1) ? bk : bv;
    float*       y = (mat == 0) ? Q  : (mat == 1) ? K  : V;

    const float4* Wr = (const float4*)(W + (size_t)row * HD);
    float acc = 0.f;
#pragma unroll
    for (int k = 0; k < HD / 256; ++k) {   // 16 float4 per lane
        float4 w  = Wr[lane + 64 * k];
        float4 xv = xs[lane + 64 * k];
        acc = fmaf(w.x, xv.x, acc);
        acc = fmaf(w.y, xv.y, acc);
        acc = fmaf(w.z, xv.z, acc);
        acc = fmaf(w.w, xv.w, acc);
    }
    acc = wave_sum(acc);
    if (lane == 0) y[row] = acc + b[row];
}

// out[i] = softmax_j(Q_i*K_j/64) . V + h[i] : one block (256 thr) per row i.
__global__ __launch_bounds__(256) void k_attn(const float* __restrict__ Q,
                                              const float* __restrict__ K,
                                              const float* __restrict__ V,
                                              const float* __restrict__ h,
                                              float* __restrict__ out) {
    __shared__ float red[12];
    const int i = blockIdx.x;
    const int t = threadIdx.x;
    const float qi = Q[i] * (1.0f / 64.0f);   // scale = 1/sqrt(4096)
    const float4* K4 = (const float4*)K;
    const float4* V4 = (const float4*)V;

    float4 kv[4], vv[4];
    float m = -3.4e38f;
#pragma unroll
    for (int k = 0; k < 4; ++k) {
        kv[k] = K4[t + 256 * k];
        vv[k] = V4[t + 256 * k];
        m = fmaxf(m, fmaxf(fmaxf(qi * kv[k].x, qi * kv[k].y),
                           fmaxf(qi * kv[k].z, qi * kv[k].w)));
    }
    m = wave_max(m);
    const int wid = t >> 6, lane = t & 63;
    if (lane == 0) red[wid] = m;
    __syncthreads();
    m = fmaxf(fmaxf(red[0], red[1]), fmaxf(red[2], red[3]));

    float se = 0.f, sv = 0.f;
#pragma unroll
    for (int k = 0; k < 4; ++k) {
        float e;
        e = __expf(fmaf(qi, kv[k].x, -m)); se += e; sv = fmaf(e, vv[k].x, sv);
        e = __expf(fmaf(qi, kv[k].y, -m)); se += e; sv = fmaf(e, vv[k].y, sv);
        e = __expf(fmaf(qi, kv[k].z, -m)); se += e; sv = fmaf(e, vv[k].z, sv);
        e = __expf(fmaf(qi, kv[k].w, -m)); se += e; sv = fmaf(e, vv[k].w, sv);
    }
    se = wave_sum(se);
    sv = wave_sum(sv);
    if (lane == 0) { red[4 + wid] = se; red[8 + wid] = sv; }
    __syncthreads();
    if (t == 0) {
        float SE = red[4] + red[5] + red[6] + red[7];
        float SV = red[8] + red[9] + red[10] + red[11];
        out[i] = SV / SE + h[i];
    }
}

// y = W2 @ o + b2 : 49152 rows x 4096. One wave per row; o staged in LDS.
__global__ __launch_bounds__(256) void k_out(const float* __restrict__ W2,
                                             const float* __restrict__ b2,
                                             const float* __restrict__ x,
                                             float* __restrict__ y) {
    __shared__ float4 xs[HD / 4];
    const float4* x4g = (const float4*)x;
#pragma unroll
    for (int k = 0; k < HD / 4 / 256; ++k)
        xs[threadIdx.x + 256 * k] = x4g[threadIdx.x + 256 * k];
    __syncthreads();

    const int lane = threadIdx.x & 63;
    const int row  = (blockIdx.x * 256 + threadIdx.x) >> 6;
    const float4* Wr = (const float4*)(W2 + (size_t)row * HD);
    float acc = 0.f;
#pragma unroll
    for (int k = 0; k < HD / 256; ++k) {   // 16 float4 per lane
        float4 w  = Wr[lane + 64 * k];
        float4 xv = xs[lane + 64 * k];
        acc = fmaf(w.x, xv.x, acc);
        acc = fmaf(w.y, xv.y, acc);
        acc = fmaf(w.z, xv.z, acc);
        acc = fmaf(w.w, xv.w, acc);
    }
    acc = wave_sum(acc);
    if (lane == 0) y[row] = acc + b2[row];
}

extern "C" void kernel_launch(void* const* d_in, const int* in_sizes, int n_in,
                              void* d_out, int out_size, void* d_ws, size_t ws_size,
                              hipStream_t stream) {
    const float* x  = (const float*)d_in[0];   // dialect_features [1024]
    const float* W1 = (const float*)d_in[1];   // [4096,1024]
    const float* b1 = (const float*)d_in[2];   // [4096]
    const float* Wq = (const float*)d_in[3];   // [4096,4096]
    const float* bq = (const float*)d_in[4];
    const float* Wk = (const float*)d_in[5];
    const float* bk = (const float*)d_in[6];
    const float* Wv = (const float*)d_in[7];
    const float* bv = (const float*)d_in[8];
    const float* W2 = (const float*)d_in[9];   // [49152,4096]
    const float* b2 = (const float*)d_in[10];  // [49152]
    float* out = (float*)d_out;                // [49152] fp32

    float* ws = (float*)d_ws;
    float* h  = ws;             // [4096]
    float* Q  = ws + 4096;      // [4096]
    float* K  = ws + 8192;      // [4096]
    float* V  = ws + 12288;     // [4096]
    float* o  = ws + 16384;     // [4096]

    k_h   <<<HD / 4,      256, 0, stream>>>(W1, x, b1, h);
    k_qkv <<<3 * HD / 4,  256, 0, stream>>>(Wq, Wk, Wv, bq, bk, bv, h, Q, K, V);
    k_attn<<<HD,          256, 0, stream>>>(Q, K, V, h, o);
    k_out <<<OUTROWS / 4, 256, 0, stream>>>(W2, b2, o, out);
}